// Round 9
// baseline (195.432 us; speedup 1.0000x reference)
//
#include <hip/hip_runtime.h>
#include <math.h>

#define BB 8
#define TT 48
#define DD 512
#define NN 1024

// ---------- z = [x ; tgt_next] @ E, LDS-tiled ----------
// grid (24,16): 32-row x 64-col tiles. Per-output accumulation is a single
// ascending-d fmaf chain -> bitwise identical to rounds 5-8.
__global__ __launch_bounds__(256) void k_gemm_z(const float* __restrict__ x,
                                                const float* __restrict__ tg,
                                                const float* __restrict__ E,
                                                float* __restrict__ z_x,
                                                float* __restrict__ z_t) {
    int rt = blockIdx.x, ct = blockIdx.y;
    int tid = threadIdx.x;
    int tr = tid >> 4;          // 0..15
    int tc = tid & 15;          // 0..15
    int row0 = rt * 32;
    int col0 = ct * 64;

    __shared__ float As[32][16];
    __shared__ float Es[16][64];

    // x-staging: thread stages As[sr][sk0], As[sr][sk0+1]
    int e2 = tid * 2;
    int sr = e2 >> 4;           // 0..31
    int sk0 = e2 & 15;
    int gr_s = row0 + sr;
    const float* srow;
    if (gr_s < BB * TT) {
        srow = x + (size_t)gr_s * DD;
    } else {
        int s = gr_s - BB * TT + 1;
        if (s > BB * TT - 1) s = BB * TT - 1;   // t=47 rows: garbage, masked by k_ln
        srow = tg + (size_t)s * DD;
    }

    // E-staging: thread stages Es[se][sc0..sc0+3]
    int se = tid >> 4;          // 0..15
    int sc0 = (tid & 15) * 4;
    const float* erow = E + col0 + sc0;

    float4 acc0 = make_float4(0.f, 0.f, 0.f, 0.f);
    float4 acc1 = make_float4(0.f, 0.f, 0.f, 0.f);

    for (int d0 = 0; d0 < DD; d0 += 16) {
        float2 xv = *reinterpret_cast<const float2*>(srow + d0 + sk0);
        float4 ev = *reinterpret_cast<const float4*>(erow + (size_t)(d0 + se) * NN);
        __syncthreads();        // prev compute done before overwrite
        As[sr][sk0] = xv.x;
        As[sr][sk0 + 1] = xv.y;
        *reinterpret_cast<float4*>(&Es[se][sc0]) = ev;
        __syncthreads();
#pragma unroll
        for (int k = 0; k < 16; k++) {
            float a0 = As[tr][k];
            float a1 = As[tr + 16][k];
            float4 e = *reinterpret_cast<const float4*>(&Es[k][tc * 4]);
            acc0.x = fmaf(a0, e.x, acc0.x);
            acc0.y = fmaf(a0, e.y, acc0.y);
            acc0.z = fmaf(a0, e.z, acc0.z);
            acc0.w = fmaf(a0, e.w, acc0.w);
            acc1.x = fmaf(a1, e.x, acc1.x);
            acc1.y = fmaf(a1, e.y, acc1.y);
            acc1.z = fmaf(a1, e.z, acc1.z);
            acc1.w = fmaf(a1, e.w, acc1.w);
        }
    }

    int gr0 = row0 + tr, gr1 = row0 + tr + 16;
    int cbase = col0 + tc * 4;
    if (gr0 < BB * TT)
        *reinterpret_cast<float4*>(z_x + (size_t)gr0 * NN + cbase) = acc0;
    else
        *reinterpret_cast<float4*>(z_t + (size_t)(gr0 - BB * TT) * NN + cbase) = acc0;
    if (gr1 < BB * TT)
        *reinterpret_cast<float4*>(z_x + (size_t)gr1 * NN + cbase) = acc1;
    else
        *reinterpret_cast<float4*>(z_t + (size_t)(gr1 - BB * TT) * NN + cbase) = acc1;
}

// ---------- LN + relu (round-3 exact) ----------
__global__ __launch_bounds__(256) void k_ln(const float* __restrict__ z_x,
                                            const float* __restrict__ z_t,
                                            float* __restrict__ xn,
                                            float* __restrict__ tn) {
    int bt = blockIdx.x;
    int t = bt % TT;
    int tid = threadIdx.x;
    __shared__ float rs_[256], rq_[256];

    const float* src = z_x + (size_t)bt * NN;
    float v0 = src[tid], v1 = src[tid + 256], v2 = src[tid + 512], v3 = src[tid + 768];
    rs_[tid] = v0 + v1 + v2 + v3;
    rq_[tid] = v0 * v0 + v1 * v1 + v2 * v2 + v3 * v3;
    __syncthreads();
    for (int off = 128; off > 0; off >>= 1) {
        if (tid < off) { rs_[tid] += rs_[tid + off]; rq_[tid] += rq_[tid + off]; }
        __syncthreads();
    }
    float mu = rs_[0] * (1.f / NN);
    float var = rq_[0] * (1.f / NN) - mu * mu;
    float rstd = rsqrtf(var + 1e-5f);
    float* xrow = xn + (size_t)bt * NN;
    xrow[tid]       = fmaxf((v0 - mu) * rstd, 0.f);
    xrow[tid + 256] = fmaxf((v1 - mu) * rstd, 0.f);
    xrow[tid + 512] = fmaxf((v2 - mu) * rstd, 0.f);
    xrow[tid + 768] = fmaxf((v3 - mu) * rstd, 0.f);
    __syncthreads();

    float* trow = tn + (size_t)bt * NN;
    if (t < TT - 1) {
        const float* s2 = z_t + (size_t)bt * NN;
        float u0 = s2[tid], u1 = s2[tid + 256], u2 = s2[tid + 512], u3 = s2[tid + 768];
        rs_[tid] = u0 + u1 + u2 + u3;
        rq_[tid] = u0 * u0 + u1 * u1 + u2 * u2 + u3 * u3;
        __syncthreads();
        for (int off = 128; off > 0; off >>= 1) {
            if (tid < off) { rs_[tid] += rs_[tid + off]; rq_[tid] += rq_[tid + off]; }
            __syncthreads();
        }
        float mu2 = rs_[0] * (1.f / NN);
        float var2 = rq_[0] * (1.f / NN) - mu2 * mu2;
        float r2 = rsqrtf(var2 + 1e-5f);
        trow[tid]       = fmaxf((u0 - mu2) * r2, 0.f);
        trow[tid + 256] = fmaxf((u1 - mu2) * r2, 0.f);
        trow[tid + 512] = fmaxf((u2 - mu2) * r2, 0.f);
        trow[tid + 768] = fmaxf((u3 - mu2) * r2, 0.f);
    } else {
        trow[tid] = 0.f; trow[tid + 256] = 0.f; trow[tid + 512] = 0.f; trow[tid + 768] = 0.f;
    }
}

// ---------- the recurrence: G in 64 NAMED registers ----------
// amdgpu_waves_per_eu(2,2) pins the occupancy target to 2 waves/EU -> 256-VGPR
// budget -> the allocator keeps g0..g63 in ARCH VGPRs (no AGPR/scratch moves).
// Branchless (wn==0 is a bit-exact no-op since xn,g >= 0). Weights via
// s_load_dwordx16 into SGPRs: zero VGPR, zero VALU cost.

typedef __attribute__((ext_vector_type(16))) float f16v;

#define GI(n) float g##n = (state == 0 && nc == cc && (n) == lane) ? 0.5f : 0.f;
#define REP64(X) X(0) X(1) X(2) X(3) X(4) X(5) X(6) X(7) X(8) X(9) X(10) X(11) X(12) X(13) \
    X(14) X(15) X(16) X(17) X(18) X(19) X(20) X(21) X(22) X(23) X(24) X(25) X(26) X(27) \
    X(28) X(29) X(30) X(31) X(32) X(33) X(34) X(35) X(36) X(37) X(38) X(39) X(40) X(41) \
    X(42) X(43) X(44) X(45) X(46) X(47) X(48) X(49) X(50) X(51) X(52) X(53) X(54) X(55) \
    X(56) X(57) X(58) X(59) X(60) X(61) X(62) X(63)

#define GS(W, I, n, A) { float wn = (W)[I]; A = fmaf(wn, g##n, A); g##n = fmaxf(g##n, wn * mh); }

__global__ __launch_bounds__(256)
__attribute__((amdgpu_waves_per_eu(2, 2)))
void k_sweep(const float* __restrict__ xn,
             const float* __restrict__ tn,
             float* __restrict__ r_part) {
    int bid = blockIdx.x;
    int ccg = bid & 3, nc = (bid >> 2) & 15, b = (bid >> 6) & 7, state = bid >> 9;
    int tid = threadIdx.x;
    int lane = tid & 63;
    int wid = __builtin_amdgcn_readfirstlane(tid >> 6);
    int cc = ccg * 4 + wid;
    int n0 = nc * 64;
    int col = cc * 64 + lane;

    REP64(GI)

    const float* wb  = xn + (size_t)b * TT * NN + n0;              // wave-uniform rows
    const float* mvb = (state ? tn : xn) + (size_t)b * TT * NN + col;
    float* rp = r_part + ((size_t)((state * 8 + b) * 16 + nc) * TT) * NN + col;

#pragma unroll 1
    for (int t = 0; t < TT; t++) {
        float mv = mvb[(size_t)t * NN];            // VMEM issued before s_loads
        const float* xrow = wb + (size_t)t * NN;
        f16v w0, w1, w2, w3;
        asm volatile("s_load_dwordx16 %0, %4, 0x0\n\t"
                     "s_load_dwordx16 %1, %4, 0x40\n\t"
                     "s_load_dwordx16 %2, %4, 0x80\n\t"
                     "s_load_dwordx16 %3, %4, 0xc0\n\t"
                     "s_waitcnt lgkmcnt(0)"
                     : "=s"(w0), "=s"(w1), "=s"(w2), "=s"(w3)
                     : "s"(xrow)
                     : "memory");
        float sc = (t < TT - 1) ? 0.5f : 0.0f;     // folds do_upd into the operand
        float mh = mv * sc;
        float a0 = 0.f, a1 = 0.f, a2 = 0.f, a3 = 0.f;
        GS(w0,0,0,a0)   GS(w0,1,1,a1)   GS(w0,2,2,a2)   GS(w0,3,3,a3)
        GS(w0,4,4,a0)   GS(w0,5,5,a1)   GS(w0,6,6,a2)   GS(w0,7,7,a3)
        GS(w0,8,8,a0)   GS(w0,9,9,a1)   GS(w0,10,10,a2) GS(w0,11,11,a3)
        GS(w0,12,12,a0) GS(w0,13,13,a1) GS(w0,14,14,a2) GS(w0,15,15,a3)
        GS(w1,0,16,a0)  GS(w1,1,17,a1)  GS(w1,2,18,a2)  GS(w1,3,19,a3)
        GS(w1,4,20,a0)  GS(w1,5,21,a1)  GS(w1,6,22,a2)  GS(w1,7,23,a3)
        GS(w1,8,24,a0)  GS(w1,9,25,a1)  GS(w1,10,26,a2) GS(w1,11,27,a3)
        GS(w1,12,28,a0) GS(w1,13,29,a1) GS(w1,14,30,a2) GS(w1,15,31,a3)
        GS(w2,0,32,a0)  GS(w2,1,33,a1)  GS(w2,2,34,a2)  GS(w2,3,35,a3)
        GS(w2,4,36,a0)  GS(w2,5,37,a1)  GS(w2,6,38,a2)  GS(w2,7,39,a3)
        GS(w2,8,40,a0)  GS(w2,9,41,a1)  GS(w2,10,42,a2) GS(w2,11,43,a3)
        GS(w2,12,44,a0) GS(w2,13,45,a1) GS(w2,14,46,a2) GS(w2,15,47,a3)
        GS(w3,0,48,a0)  GS(w3,1,49,a1)  GS(w3,2,50,a2)  GS(w3,3,51,a3)
        GS(w3,4,52,a0)  GS(w3,5,53,a1)  GS(w3,6,54,a2)  GS(w3,7,55,a3)
        GS(w3,8,56,a0)  GS(w3,9,57,a1)  GS(w3,10,58,a2) GS(w3,11,59,a3)
        GS(w3,12,60,a0) GS(w3,13,61,a1) GS(w3,14,62,a2) GS(w3,15,63,a3)
        rp[(size_t)t * NN] = (a0 + a1) + (a2 + a3);
    }
}

// ---------- reduce partials over nc, mix, @Dy, relu (round-3 exact) ----------
__global__ __launch_bounds__(256) void k_y(const float* __restrict__ r_part,
                                           const float* __restrict__ Dy,
                                           const float* __restrict__ mixp,
                                           float* __restrict__ out) {
    int bb = blockIdx.x;
    int tg = bb & 15, b = bb >> 4;
    int tid = threadIdx.x;
    __shared__ float mixs[3][NN];
    float alpha = 1.f / (1.f + expf(-mixp[0]));

#pragma unroll
    for (int tt = 0; tt < 3; tt++) {
        int t = tg * 3 + tt;
        float spx = 0.f, spy = 0.f, spz = 0.f, spw = 0.f;
        float stx = 0.f, sty = 0.f, stz = 0.f, stw = 0.f;
#pragma unroll
        for (int nc = 0; nc < 16; nc++) {
            int bidp = (b * 16 + nc);
            int bidt = ((8 + b) * 16 + nc);
            float4 p = *reinterpret_cast<const float4*>(r_part + ((size_t)bidp * TT + t) * NN + tid * 4);
            float4 q = *reinterpret_cast<const float4*>(r_part + ((size_t)bidt * TT + t) * NN + tid * 4);
            spx += p.x; spy += p.y; spz += p.z; spw += p.w;
            stx += q.x; sty += q.y; stz += q.z; stw += q.w;
        }
        float4 m4;
        m4.x = alpha * spx + (1.f - alpha) * stx;
        m4.y = alpha * spy + (1.f - alpha) * sty;
        m4.z = alpha * spz + (1.f - alpha) * stz;
        m4.w = alpha * spw + (1.f - alpha) * stw;
        *reinterpret_cast<float4*>(&mixs[tt][tid * 4]) = m4;
    }
    __syncthreads();

    float acc[3][2];
#pragma unroll
    for (int tt = 0; tt < 3; tt++) { acc[tt][0] = 0.f; acc[tt][1] = 0.f; }

    for (int m = 0; m < NN; m += 4) {
        float w[3][4];
#pragma unroll
        for (int tt = 0; tt < 3; tt++) {
            float4 v = *reinterpret_cast<const float4*>(&mixs[tt][m]);
            w[tt][0] = v.x; w[tt][1] = v.y; w[tt][2] = v.z; w[tt][3] = v.w;
        }
#pragma unroll
        for (int j = 0; j < 4; j++) {
            float d0 = Dy[(size_t)(m + j) * DD + tid];
            float d1 = Dy[(size_t)(m + j) * DD + tid + 256];
#pragma unroll
            for (int tt = 0; tt < 3; tt++) {
                acc[tt][0] = fmaf(w[tt][j], d0, acc[tt][0]);
                acc[tt][1] = fmaf(w[tt][j], d1, acc[tt][1]);
            }
        }
    }
#pragma unroll
    for (int tt = 0; tt < 3; tt++) {
        int t = tg * 3 + tt;
        out[((size_t)b * TT + t) * DD + tid]       = fmaxf(acc[tt][0], 0.f);
        out[((size_t)b * TT + t) * DD + tid + 256] = fmaxf(acc[tt][1], 0.f);
    }
}

extern "C" void kernel_launch(void* const* d_in, const int* in_sizes, int n_in,
                              void* d_out, int out_size, void* d_ws, size_t ws_size,
                              hipStream_t stream) {
    const float* x    = (const float*)d_in[0];   // [8,48,512]
    const float* tg   = (const float*)d_in[1];   // [8,48,512]
    const float* E    = (const float*)d_in[2];   // [512,1024]
    const float* Dy   = (const float*)d_in[3];   // [1024,512]
    const float* mixp = (const float*)d_in[4];   // scalar
    float* out = (float*)d_out;                  // [8,48,512]

    float* ws = (float*)d_ws;
    float* z_x    = ws;                               // 384*1024
    float* z_t    = z_x + (size_t)384 * 1024;
    float* xn     = z_t + (size_t)384 * 1024;
    float* tn     = xn + (size_t)384 * 1024;
    float* r_part = tn + (size_t)384 * 1024;          // 256 chunks * 48 * 1024 floats

    k_gemm_z<<<dim3(24, 16), 256, 0, stream>>>(x, tg, E, z_x, z_t);
    k_ln<<<384, 256, 0, stream>>>(z_x, z_t, xn, tn);
    k_sweep<<<1024, 256, 0, stream>>>(xn, tn, r_part);
    k_y<<<128, 256, 0, stream>>>(r_part, Dy, mixp, out);
}

// Round 10
// 165.521 us; speedup vs baseline: 1.1807x; 1.1807x over previous
//
#include <hip/hip_runtime.h>
#include <math.h>

#define BB 8
#define TT 48
#define DD 512
#define NN 1024

// ---------- z = [x ; tgt_next] @ E, LDS-tiled (round-9 exact) ----------
__global__ __launch_bounds__(256) void k_gemm_z(const float* __restrict__ x,
                                                const float* __restrict__ tg,
                                                const float* __restrict__ E,
                                                float* __restrict__ z_x,
                                                float* __restrict__ z_t) {
    int rt = blockIdx.x, ct = blockIdx.y;
    int tid = threadIdx.x;
    int tr = tid >> 4;          // 0..15
    int tc = tid & 15;          // 0..15
    int row0 = rt * 32;
    int col0 = ct * 64;

    __shared__ float As[32][16];
    __shared__ float Es[16][64];

    int e2 = tid * 2;
    int sr = e2 >> 4;           // 0..31
    int sk0 = e2 & 15;
    int gr_s = row0 + sr;
    const float* srow;
    if (gr_s < BB * TT) {
        srow = x + (size_t)gr_s * DD;
    } else {
        int s = gr_s - BB * TT + 1;
        if (s > BB * TT - 1) s = BB * TT - 1;   // t=47 rows: garbage, masked by k_ln
        srow = tg + (size_t)s * DD;
    }

    int se = tid >> 4;          // 0..15
    int sc0 = (tid & 15) * 4;
    const float* erow = E + col0 + sc0;

    float4 acc0 = make_float4(0.f, 0.f, 0.f, 0.f);
    float4 acc1 = make_float4(0.f, 0.f, 0.f, 0.f);

    for (int d0 = 0; d0 < DD; d0 += 16) {
        float2 xv = *reinterpret_cast<const float2*>(srow + d0 + sk0);
        float4 ev = *reinterpret_cast<const float4*>(erow + (size_t)(d0 + se) * NN);
        __syncthreads();
        As[sr][sk0] = xv.x;
        As[sr][sk0 + 1] = xv.y;
        *reinterpret_cast<float4*>(&Es[se][sc0]) = ev;
        __syncthreads();
#pragma unroll
        for (int k = 0; k < 16; k++) {
            float a0 = As[tr][k];
            float a1 = As[tr + 16][k];
            float4 e = *reinterpret_cast<const float4*>(&Es[k][tc * 4]);
            acc0.x = fmaf(a0, e.x, acc0.x);
            acc0.y = fmaf(a0, e.y, acc0.y);
            acc0.z = fmaf(a0, e.z, acc0.z);
            acc0.w = fmaf(a0, e.w, acc0.w);
            acc1.x = fmaf(a1, e.x, acc1.x);
            acc1.y = fmaf(a1, e.y, acc1.y);
            acc1.z = fmaf(a1, e.z, acc1.z);
            acc1.w = fmaf(a1, e.w, acc1.w);
        }
    }

    int gr0 = row0 + tr, gr1 = row0 + tr + 16;
    int cbase = col0 + tc * 4;
    if (gr0 < BB * TT)
        *reinterpret_cast<float4*>(z_x + (size_t)gr0 * NN + cbase) = acc0;
    else
        *reinterpret_cast<float4*>(z_t + (size_t)(gr0 - BB * TT) * NN + cbase) = acc0;
    if (gr1 < BB * TT)
        *reinterpret_cast<float4*>(z_x + (size_t)gr1 * NN + cbase) = acc1;
    else
        *reinterpret_cast<float4*>(z_t + (size_t)(gr1 - BB * TT) * NN + cbase) = acc1;
}

// ---------- LN + relu (round-3 exact) ----------
__global__ __launch_bounds__(256) void k_ln(const float* __restrict__ z_x,
                                            const float* __restrict__ z_t,
                                            float* __restrict__ xn,
                                            float* __restrict__ tn) {
    int bt = blockIdx.x;
    int t = bt % TT;
    int tid = threadIdx.x;
    __shared__ float rs_[256], rq_[256];

    const float* src = z_x + (size_t)bt * NN;
    float v0 = src[tid], v1 = src[tid + 256], v2 = src[tid + 512], v3 = src[tid + 768];
    rs_[tid] = v0 + v1 + v2 + v3;
    rq_[tid] = v0 * v0 + v1 * v1 + v2 * v2 + v3 * v3;
    __syncthreads();
    for (int off = 128; off > 0; off >>= 1) {
        if (tid < off) { rs_[tid] += rs_[tid + off]; rq_[tid] += rq_[tid + off]; }
        __syncthreads();
    }
    float mu = rs_[0] * (1.f / NN);
    float var = rq_[0] * (1.f / NN) - mu * mu;
    float rstd = rsqrtf(var + 1e-5f);
    float* xrow = xn + (size_t)bt * NN;
    xrow[tid]       = fmaxf((v0 - mu) * rstd, 0.f);
    xrow[tid + 256] = fmaxf((v1 - mu) * rstd, 0.f);
    xrow[tid + 512] = fmaxf((v2 - mu) * rstd, 0.f);
    xrow[tid + 768] = fmaxf((v3 - mu) * rstd, 0.f);
    __syncthreads();

    float* trow = tn + (size_t)bt * NN;
    if (t < TT - 1) {
        const float* s2 = z_t + (size_t)bt * NN;
        float u0 = s2[tid], u1 = s2[tid + 256], u2 = s2[tid + 512], u3 = s2[tid + 768];
        rs_[tid] = u0 + u1 + u2 + u3;
        rq_[tid] = u0 * u0 + u1 * u1 + u2 * u2 + u3 * u3;
        __syncthreads();
        for (int off = 128; off > 0; off >>= 1) {
            if (tid < off) { rs_[tid] += rs_[tid + off]; rq_[tid] += rq_[tid + off]; }
            __syncthreads();
        }
        float mu2 = rs_[0] * (1.f / NN);
        float var2 = rq_[0] * (1.f / NN) - mu2 * mu2;
        float r2 = rsqrtf(var2 + 1e-5f);
        trow[tid]       = fmaxf((u0 - mu2) * r2, 0.f);
        trow[tid + 256] = fmaxf((u1 - mu2) * r2, 0.f);
        trow[tid + 512] = fmaxf((u2 - mu2) * r2, 0.f);
        trow[tid + 768] = fmaxf((u3 - mu2) * r2, 0.f);
    } else {
        trow[tid] = 0.f; trow[tid + 256] = 0.f; trow[tid + 512] = 0.f; trow[tid + 768] = 0.f;
    }
}

// ---------- the recurrence: G forced into arch VGPRs via asm constraints ----------
// Each row-step is exactly 3 VALU instrs with hard register classes:
//   v_fmac_f32 A, wn(s), g(v)   ; A += wn*g   (single-rounded FMA == fmaf)
//   v_mul_f32  tmp, wn(s), mh(v)
//   v_max_f32  g, g, tmp
// "+v" on g forces arch-VGPR residence (no AGPR shuttling, no scratch).
// Weights via s_load_dwordx16 -> SGPRs (zero VGPR/VALU cost).

typedef __attribute__((ext_vector_type(16))) float f16v;

#define GI(n) float g##n = (state == 0 && nc == cc && (n) == lane) ? 0.5f : 0.f;
#define REP64(X) X(0) X(1) X(2) X(3) X(4) X(5) X(6) X(7) X(8) X(9) X(10) X(11) X(12) X(13) \
    X(14) X(15) X(16) X(17) X(18) X(19) X(20) X(21) X(22) X(23) X(24) X(25) X(26) X(27) \
    X(28) X(29) X(30) X(31) X(32) X(33) X(34) X(35) X(36) X(37) X(38) X(39) X(40) X(41) \
    X(42) X(43) X(44) X(45) X(46) X(47) X(48) X(49) X(50) X(51) X(52) X(53) X(54) X(55) \
    X(56) X(57) X(58) X(59) X(60) X(61) X(62) X(63)

#define GS(W, I, n, A) { float wn_ = (W)[I]; float tmp_;                         \
    asm("v_fmac_f32 %[a], %[w], %[g]\n\t"                                        \
        "v_mul_f32 %[t], %[w], %[m]\n\t"                                         \
        "v_max_f32 %[g], %[g], %[t]"                                             \
        : [a]"+v"(A), [g]"+v"(g##n), [t]"=&v"(tmp_)                              \
        : [w]"s"(wn_), [m]"v"(mh)); }

__global__ __launch_bounds__(256)
__attribute__((amdgpu_waves_per_eu(2, 2)))
void k_sweep(const float* __restrict__ xn,
             const float* __restrict__ tn,
             float* __restrict__ r_part) {
    int bid = blockIdx.x;
    int ccg = bid & 3, nc = (bid >> 2) & 15, b = (bid >> 6) & 7, state = bid >> 9;
    int tid = threadIdx.x;
    int lane = tid & 63;
    int wid = __builtin_amdgcn_readfirstlane(tid >> 6);
    int cc = ccg * 4 + wid;
    int n0 = nc * 64;
    int col = cc * 64 + lane;

    REP64(GI)

    const float* wb  = xn + (size_t)b * TT * NN + n0;              // wave-uniform rows
    const float* mvb = (state ? tn : xn) + (size_t)b * TT * NN + col;
    float* rp = r_part + ((size_t)((state * 8 + b) * 16 + nc) * TT) * NN + col;

#pragma unroll 1
    for (int t = 0; t < TT; t++) {
        float mv = mvb[(size_t)t * NN];            // VMEM issued before s_loads
        const float* xrow = wb + (size_t)t * NN;
        f16v w0, w1, w2, w3;
        asm volatile("s_load_dwordx16 %0, %4, 0x0\n\t"
                     "s_load_dwordx16 %1, %4, 0x40\n\t"
                     "s_load_dwordx16 %2, %4, 0x80\n\t"
                     "s_load_dwordx16 %3, %4, 0xc0\n\t"
                     "s_waitcnt lgkmcnt(0)"
                     : "=s"(w0), "=s"(w1), "=s"(w2), "=s"(w3)
                     : "s"(xrow)
                     : "memory");
        float sc = (t < TT - 1) ? 0.5f : 0.0f;     // folds do_upd into the operand
        float mh = mv * sc;
        float a0 = 0.f, a1 = 0.f, a2 = 0.f, a3 = 0.f;
        GS(w0,0,0,a0)   GS(w0,1,1,a1)   GS(w0,2,2,a2)   GS(w0,3,3,a3)
        GS(w0,4,4,a0)   GS(w0,5,5,a1)   GS(w0,6,6,a2)   GS(w0,7,7,a3)
        GS(w0,8,8,a0)   GS(w0,9,9,a1)   GS(w0,10,10,a2) GS(w0,11,11,a3)
        GS(w0,12,12,a0) GS(w0,13,13,a1) GS(w0,14,14,a2) GS(w0,15,15,a3)
        GS(w1,0,16,a0)  GS(w1,1,17,a1)  GS(w1,2,18,a2)  GS(w1,3,19,a3)
        GS(w1,4,20,a0)  GS(w1,5,21,a1)  GS(w1,6,22,a2)  GS(w1,7,23,a3)
        GS(w1,8,24,a0)  GS(w1,9,25,a1)  GS(w1,10,26,a2) GS(w1,11,27,a3)
        GS(w1,12,28,a0) GS(w1,13,29,a1) GS(w1,14,30,a2) GS(w1,15,31,a3)
        GS(w2,0,32,a0)  GS(w2,1,33,a1)  GS(w2,2,34,a2)  GS(w2,3,35,a3)
        GS(w2,4,36,a0)  GS(w2,5,37,a1)  GS(w2,6,38,a2)  GS(w2,7,39,a3)
        GS(w2,8,40,a0)  GS(w2,9,41,a1)  GS(w2,10,42,a2) GS(w2,11,43,a3)
        GS(w2,12,44,a0) GS(w2,13,45,a1) GS(w2,14,46,a2) GS(w2,15,47,a3)
        GS(w3,0,48,a0)  GS(w3,1,49,a1)  GS(w3,2,50,a2)  GS(w3,3,51,a3)
        GS(w3,4,52,a0)  GS(w3,5,53,a1)  GS(w3,6,54,a2)  GS(w3,7,55,a3)
        GS(w3,8,56,a0)  GS(w3,9,57,a1)  GS(w3,10,58,a2) GS(w3,11,59,a3)
        GS(w3,12,60,a0) GS(w3,13,61,a1) GS(w3,14,62,a2) GS(w3,15,63,a3)
        rp[(size_t)t * NN] = (a0 + a1) + (a2 + a3);
    }
}

// ---------- reduce partials over nc, mix, @Dy, relu (round-3 exact) ----------
__global__ __launch_bounds__(256) void k_y(const float* __restrict__ r_part,
                                           const float* __restrict__ Dy,
                                           const float* __restrict__ mixp,
                                           float* __restrict__ out) {
    int bb = blockIdx.x;
    int tg = bb & 15, b = bb >> 4;
    int tid = threadIdx.x;
    __shared__ float mixs[3][NN];
    float alpha = 1.f / (1.f + expf(-mixp[0]));

#pragma unroll
    for (int tt = 0; tt < 3; tt++) {
        int t = tg * 3 + tt;
        float spx = 0.f, spy = 0.f, spz = 0.f, spw = 0.f;
        float stx = 0.f, sty = 0.f, stz = 0.f, stw = 0.f;
#pragma unroll
        for (int nc = 0; nc < 16; nc++) {
            int bidp = (b * 16 + nc);
            int bidt = ((8 + b) * 16 + nc);
            float4 p = *reinterpret_cast<const float4*>(r_part + ((size_t)bidp * TT + t) * NN + tid * 4);
            float4 q = *reinterpret_cast<const float4*>(r_part + ((size_t)bidt * TT + t) * NN + tid * 4);
            spx += p.x; spy += p.y; spz += p.z; spw += p.w;
            stx += q.x; sty += q.y; stz += q.z; stw += q.w;
        }
        float4 m4;
        m4.x = alpha * spx + (1.f - alpha) * stx;
        m4.y = alpha * spy + (1.f - alpha) * sty;
        m4.z = alpha * spz + (1.f - alpha) * stz;
        m4.w = alpha * spw + (1.f - alpha) * stw;
        *reinterpret_cast<float4*>(&mixs[tt][tid * 4]) = m4;
    }
    __syncthreads();

    float acc[3][2];
#pragma unroll
    for (int tt = 0; tt < 3; tt++) { acc[tt][0] = 0.f; acc[tt][1] = 0.f; }

    for (int m = 0; m < NN; m += 4) {
        float w[3][4];
#pragma unroll
        for (int tt = 0; tt < 3; tt++) {
            float4 v = *reinterpret_cast<const float4*>(&mixs[tt][m]);
            w[tt][0] = v.x; w[tt][1] = v.y; w[tt][2] = v.z; w[tt][3] = v.w;
        }
#pragma unroll
        for (int j = 0; j < 4; j++) {
            float d0 = Dy[(size_t)(m + j) * DD + tid];
            float d1 = Dy[(size_t)(m + j) * DD + tid + 256];
#pragma unroll
            for (int tt = 0; tt < 3; tt++) {
                acc[tt][0] = fmaf(w[tt][j], d0, acc[tt][0]);
                acc[tt][1] = fmaf(w[tt][j], d1, acc[tt][1]);
            }
        }
    }
#pragma unroll
    for (int tt = 0; tt < 3; tt++) {
        int t = tg * 3 + tt;
        out[((size_t)b * TT + t) * DD + tid]       = fmaxf(acc[tt][0], 0.f);
        out[((size_t)b * TT + t) * DD + tid + 256] = fmaxf(acc[tt][1], 0.f);
    }
}

extern "C" void kernel_launch(void* const* d_in, const int* in_sizes, int n_in,
                              void* d_out, int out_size, void* d_ws, size_t ws_size,
                              hipStream_t stream) {
    const float* x    = (const float*)d_in[0];   // [8,48,512]
    const float* tg   = (const float*)d_in[1];   // [8,48,512]
    const float* E    = (const float*)d_in[2];   // [512,1024]
    const float* Dy   = (const float*)d_in[3];   // [1024,512]
    const float* mixp = (const float*)d_in[4];   // scalar
    float* out = (float*)d_out;                  // [8,48,512]

    float* ws = (float*)d_ws;
    float* z_x    = ws;                               // 384*1024
    float* z_t    = z_x + (size_t)384 * 1024;
    float* xn     = z_t + (size_t)384 * 1024;
    float* tn     = xn + (size_t)384 * 1024;
    float* r_part = tn + (size_t)384 * 1024;          // 256 chunks * 48 * 1024 floats

    k_gemm_z<<<dim3(24, 16), 256, 0, stream>>>(x, tg, E, z_x, z_t);
    k_ln<<<384, 256, 0, stream>>>(z_x, z_t, xn, tn);
    k_sweep<<<1024, 256, 0, stream>>>(xn, tn, r_part);
    k_y<<<128, 256, 0, stream>>>(r_part, Dy, mixp, out);
}

// Round 11
// 143.137 us; speedup vs baseline: 1.3654x; 1.1564x over previous
//
#include <hip/hip_runtime.h>
#include <math.h>

#define BB 8
#define TT 48
#define DD 512
#define NN 1024

// ---------- z = [x ; tgt_next] @ E, LDS-tiled (round-9 exact) ----------
__global__ __launch_bounds__(256) void k_gemm_z(const float* __restrict__ x,
                                                const float* __restrict__ tg,
                                                const float* __restrict__ E,
                                                float* __restrict__ z_x,
                                                float* __restrict__ z_t) {
    int rt = blockIdx.x, ct = blockIdx.y;
    int tid = threadIdx.x;
    int tr = tid >> 4;          // 0..15
    int tc = tid & 15;          // 0..15
    int row0 = rt * 32;
    int col0 = ct * 64;

    __shared__ float As[32][16];
    __shared__ float Es[16][64];

    int e2 = tid * 2;
    int sr = e2 >> 4;           // 0..31
    int sk0 = e2 & 15;
    int gr_s = row0 + sr;
    const float* srow;
    if (gr_s < BB * TT) {
        srow = x + (size_t)gr_s * DD;
    } else {
        int s = gr_s - BB * TT + 1;
        if (s > BB * TT - 1) s = BB * TT - 1;   // t=47 rows: garbage, masked by k_ln
        srow = tg + (size_t)s * DD;
    }

    int se = tid >> 4;          // 0..15
    int sc0 = (tid & 15) * 4;
    const float* erow = E + col0 + sc0;

    float4 acc0 = make_float4(0.f, 0.f, 0.f, 0.f);
    float4 acc1 = make_float4(0.f, 0.f, 0.f, 0.f);

    for (int d0 = 0; d0 < DD; d0 += 16) {
        float2 xv = *reinterpret_cast<const float2*>(srow + d0 + sk0);
        float4 ev = *reinterpret_cast<const float4*>(erow + (size_t)(d0 + se) * NN);
        __syncthreads();
        As[sr][sk0] = xv.x;
        As[sr][sk0 + 1] = xv.y;
        *reinterpret_cast<float4*>(&Es[se][sc0]) = ev;
        __syncthreads();
#pragma unroll
        for (int k = 0; k < 16; k++) {
            float a0 = As[tr][k];
            float a1 = As[tr + 16][k];
            float4 e = *reinterpret_cast<const float4*>(&Es[k][tc * 4]);
            acc0.x = fmaf(a0, e.x, acc0.x);
            acc0.y = fmaf(a0, e.y, acc0.y);
            acc0.z = fmaf(a0, e.z, acc0.z);
            acc0.w = fmaf(a0, e.w, acc0.w);
            acc1.x = fmaf(a1, e.x, acc1.x);
            acc1.y = fmaf(a1, e.y, acc1.y);
            acc1.z = fmaf(a1, e.z, acc1.z);
            acc1.w = fmaf(a1, e.w, acc1.w);
        }
    }

    int gr0 = row0 + tr, gr1 = row0 + tr + 16;
    int cbase = col0 + tc * 4;
    if (gr0 < BB * TT)
        *reinterpret_cast<float4*>(z_x + (size_t)gr0 * NN + cbase) = acc0;
    else
        *reinterpret_cast<float4*>(z_t + (size_t)(gr0 - BB * TT) * NN + cbase) = acc0;
    if (gr1 < BB * TT)
        *reinterpret_cast<float4*>(z_x + (size_t)gr1 * NN + cbase) = acc1;
    else
        *reinterpret_cast<float4*>(z_t + (size_t)(gr1 - BB * TT) * NN + cbase) = acc1;
}

// ---------- LN + relu (round-3 exact) ----------
__global__ __launch_bounds__(256) void k_ln(const float* __restrict__ z_x,
                                            const float* __restrict__ z_t,
                                            float* __restrict__ xn,
                                            float* __restrict__ tn) {
    int bt = blockIdx.x;
    int t = bt % TT;
    int tid = threadIdx.x;
    __shared__ float rs_[256], rq_[256];

    const float* src = z_x + (size_t)bt * NN;
    float v0 = src[tid], v1 = src[tid + 256], v2 = src[tid + 512], v3 = src[tid + 768];
    rs_[tid] = v0 + v1 + v2 + v3;
    rq_[tid] = v0 * v0 + v1 * v1 + v2 * v2 + v3 * v3;
    __syncthreads();
    for (int off = 128; off > 0; off >>= 1) {
        if (tid < off) { rs_[tid] += rs_[tid + off]; rq_[tid] += rq_[tid + off]; }
        __syncthreads();
    }
    float mu = rs_[0] * (1.f / NN);
    float var = rq_[0] * (1.f / NN) - mu * mu;
    float rstd = rsqrtf(var + 1e-5f);
    float* xrow = xn + (size_t)bt * NN;
    xrow[tid]       = fmaxf((v0 - mu) * rstd, 0.f);
    xrow[tid + 256] = fmaxf((v1 - mu) * rstd, 0.f);
    xrow[tid + 512] = fmaxf((v2 - mu) * rstd, 0.f);
    xrow[tid + 768] = fmaxf((v3 - mu) * rstd, 0.f);
    __syncthreads();

    float* trow = tn + (size_t)bt * NN;
    if (t < TT - 1) {
        const float* s2 = z_t + (size_t)bt * NN;
        float u0 = s2[tid], u1 = s2[tid + 256], u2 = s2[tid + 512], u3 = s2[tid + 768];
        rs_[tid] = u0 + u1 + u2 + u3;
        rq_[tid] = u0 * u0 + u1 * u1 + u2 * u2 + u3 * u3;
        __syncthreads();
        for (int off = 128; off > 0; off >>= 1) {
            if (tid < off) { rs_[tid] += rs_[tid + off]; rq_[tid] += rq_[tid + off]; }
            __syncthreads();
        }
        float mu2 = rs_[0] * (1.f / NN);
        float var2 = rq_[0] * (1.f / NN) - mu2 * mu2;
        float r2 = rsqrtf(var2 + 1e-5f);
        trow[tid]       = fmaxf((u0 - mu2) * r2, 0.f);
        trow[tid + 256] = fmaxf((u1 - mu2) * r2, 0.f);
        trow[tid + 512] = fmaxf((u2 - mu2) * r2, 0.f);
        trow[tid + 768] = fmaxf((u3 - mu2) * r2, 0.f);
    } else {
        trow[tid] = 0.f; trow[tid + 256] = 0.f; trow[tid + 512] = 0.f; trow[tid + 768] = 0.f;
    }
}

// ---------- the recurrence: G forced into arch VGPRs via asm constraints ----------
// Round-10 body, occupancy cap relaxed 2 -> 4 waves/EU (88 VGPR fits the 128
// budget; 16 waves/CU all co-resident hide the per-t s_load/lgkmcnt stall).

typedef __attribute__((ext_vector_type(16))) float f16v;

#define GI(n) float g##n = (state == 0 && nc == cc && (n) == lane) ? 0.5f : 0.f;
#define REP64(X) X(0) X(1) X(2) X(3) X(4) X(5) X(6) X(7) X(8) X(9) X(10) X(11) X(12) X(13) \
    X(14) X(15) X(16) X(17) X(18) X(19) X(20) X(21) X(22) X(23) X(24) X(25) X(26) X(27) \
    X(28) X(29) X(30) X(31) X(32) X(33) X(34) X(35) X(36) X(37) X(38) X(39) X(40) X(41) \
    X(42) X(43) X(44) X(45) X(46) X(47) X(48) X(49) X(50) X(51) X(52) X(53) X(54) X(55) \
    X(56) X(57) X(58) X(59) X(60) X(61) X(62) X(63)

#define GS(W, I, n, A) { float wn_ = (W)[I]; float tmp_;                         \
    asm("v_fmac_f32 %[a], %[w], %[g]\n\t"                                        \
        "v_mul_f32 %[t], %[w], %[m]\n\t"                                         \
        "v_max_f32 %[g], %[g], %[t]"                                             \
        : [a]"+v"(A), [g]"+v"(g##n), [t]"=&v"(tmp_)                              \
        : [w]"s"(wn_), [m]"v"(mh)); }

__global__ __launch_bounds__(256)
__attribute__((amdgpu_waves_per_eu(4, 4)))
void k_sweep(const float* __restrict__ xn,
             const float* __restrict__ tn,
             float* __restrict__ r_part) {
    int bid = blockIdx.x;
    int ccg = bid & 3, nc = (bid >> 2) & 15, b = (bid >> 6) & 7, state = bid >> 9;
    int tid = threadIdx.x;
    int lane = tid & 63;
    int wid = __builtin_amdgcn_readfirstlane(tid >> 6);
    int cc = ccg * 4 + wid;
    int n0 = nc * 64;
    int col = cc * 64 + lane;

    REP64(GI)

    const float* wb  = xn + (size_t)b * TT * NN + n0;              // wave-uniform rows
    const float* mvb = (state ? tn : xn) + (size_t)b * TT * NN + col;
    float* rp = r_part + ((size_t)((state * 8 + b) * 16 + nc) * TT) * NN + col;

#pragma unroll 1
    for (int t = 0; t < TT; t++) {
        float mv = mvb[(size_t)t * NN];            // VMEM issued before s_loads
        const float* xrow = wb + (size_t)t * NN;
        f16v w0, w1, w2, w3;
        asm volatile("s_load_dwordx16 %0, %4, 0x0\n\t"
                     "s_load_dwordx16 %1, %4, 0x40\n\t"
                     "s_load_dwordx16 %2, %4, 0x80\n\t"
                     "s_load_dwordx16 %3, %4, 0xc0\n\t"
                     "s_waitcnt lgkmcnt(0)"
                     : "=s"(w0), "=s"(w1), "=s"(w2), "=s"(w3)
                     : "s"(xrow)
                     : "memory");
        float sc = (t < TT - 1) ? 0.5f : 0.0f;     // folds do_upd into the operand
        float mh = mv * sc;
        float a0 = 0.f, a1 = 0.f, a2 = 0.f, a3 = 0.f;
        GS(w0,0,0,a0)   GS(w0,1,1,a1)   GS(w0,2,2,a2)   GS(w0,3,3,a3)
        GS(w0,4,4,a0)   GS(w0,5,5,a1)   GS(w0,6,6,a2)   GS(w0,7,7,a3)
        GS(w0,8,8,a0)   GS(w0,9,9,a1)   GS(w0,10,10,a2) GS(w0,11,11,a3)
        GS(w0,12,12,a0) GS(w0,13,13,a1) GS(w0,14,14,a2) GS(w0,15,15,a3)
        GS(w1,0,16,a0)  GS(w1,1,17,a1)  GS(w1,2,18,a2)  GS(w1,3,19,a3)
        GS(w1,4,20,a0)  GS(w1,5,21,a1)  GS(w1,6,22,a2)  GS(w1,7,23,a3)
        GS(w1,8,24,a0)  GS(w1,9,25,a1)  GS(w1,10,26,a2) GS(w1,11,27,a3)
        GS(w1,12,28,a0) GS(w1,13,29,a1) GS(w1,14,30,a2) GS(w1,15,31,a3)
        GS(w2,0,32,a0)  GS(w2,1,33,a1)  GS(w2,2,34,a2)  GS(w2,3,35,a3)
        GS(w2,4,36,a0)  GS(w2,5,37,a1)  GS(w2,6,38,a2)  GS(w2,7,39,a3)
        GS(w2,8,40,a0)  GS(w2,9,41,a1)  GS(w2,10,42,a2) GS(w2,11,43,a3)
        GS(w2,12,44,a0) GS(w2,13,45,a1) GS(w2,14,46,a2) GS(w2,15,47,a3)
        GS(w3,0,48,a0)  GS(w3,1,49,a1)  GS(w3,2,50,a2)  GS(w3,3,51,a3)
        GS(w3,4,52,a0)  GS(w3,5,53,a1)  GS(w3,6,54,a2)  GS(w3,7,55,a3)
        GS(w3,8,56,a0)  GS(w3,9,57,a1)  GS(w3,10,58,a2) GS(w3,11,59,a3)
        GS(w3,12,60,a0) GS(w3,13,61,a1) GS(w3,14,62,a2) GS(w3,15,63,a3)
        rp[(size_t)t * NN] = (a0 + a1) + (a2 + a3);
    }
}

// ---------- reduce partials over nc + mix (identical component order to old k_y) ----------
__global__ __launch_bounds__(256) void k_mix(const float* __restrict__ r_part,
                                             const float* __restrict__ mixp,
                                             float* __restrict__ mix) {
    int bt = blockIdx.x;            // b*TT + t
    int b = bt / TT, t = bt % TT;
    int tid = threadIdx.x;
    int c0 = tid * 4;
    float alpha = 1.f / (1.f + expf(-mixp[0]));

    float spx = 0.f, spy = 0.f, spz = 0.f, spw = 0.f;
    float stx = 0.f, sty = 0.f, stz = 0.f, stw = 0.f;
#pragma unroll
    for (int nc = 0; nc < 16; nc++) {
        int bidp = (b * 16 + nc);
        int bidt = ((8 + b) * 16 + nc);
        float4 p = *reinterpret_cast<const float4*>(r_part + ((size_t)bidp * TT + t) * NN + c0);
        float4 q = *reinterpret_cast<const float4*>(r_part + ((size_t)bidt * TT + t) * NN + c0);
        spx += p.x; spy += p.y; spz += p.z; spw += p.w;
        stx += q.x; sty += q.y; stz += q.z; stw += q.w;
    }
    float4 m4;
    m4.x = alpha * spx + (1.f - alpha) * stx;
    m4.y = alpha * spy + (1.f - alpha) * sty;
    m4.z = alpha * spz + (1.f - alpha) * stz;
    m4.w = alpha * spw + (1.f - alpha) * stw;
    *reinterpret_cast<float4*>(mix + (size_t)bt * NN + c0) = m4;
}

// ---------- y = relu(mix @ Dy), LDS-tiled; per-output ascending-m fmaf chain ----------
// grid (8, 24): 16-row x 64-col tiles, K = 1024 in tiles of 16. Chain order over m
// is strictly ascending -> bit-identical to the old k_y accumulation.
__global__ __launch_bounds__(256) void k_y2(const float* __restrict__ mix,
                                            const float* __restrict__ Dy,
                                            float* __restrict__ out) {
    int ct = blockIdx.x;            // 0..7
    int rt = blockIdx.y;            // 0..23
    int tid = threadIdx.x;
    int row0 = rt * 16;
    int col0 = ct * 64;
    int r = tid >> 4;               // 0..15
    int tc = tid & 15;              // 0..15

    __shared__ float As[16][16];
    __shared__ float Ds[16][64];

    int sr = tid >> 4, sk = tid & 15;           // As staging: 1 scalar/thread
    int se = tid >> 4, sc0 = (tid & 15) * 4;    // Ds staging: 1 float4/thread

    float4 acc = make_float4(0.f, 0.f, 0.f, 0.f);

    for (int m0 = 0; m0 < NN; m0 += 16) {
        float av = mix[(size_t)(row0 + sr) * NN + m0 + sk];
        float4 dv = *reinterpret_cast<const float4*>(Dy + (size_t)(m0 + se) * DD + col0 + sc0);
        __syncthreads();
        As[sr][sk] = av;
        *reinterpret_cast<float4*>(&Ds[se][sc0]) = dv;
        __syncthreads();
#pragma unroll
        for (int k = 0; k < 16; k++) {
            float a = As[r][k];
            float4 e = *reinterpret_cast<const float4*>(&Ds[k][tc * 4]);
            acc.x = fmaf(a, e.x, acc.x);
            acc.y = fmaf(a, e.y, acc.y);
            acc.z = fmaf(a, e.z, acc.z);
            acc.w = fmaf(a, e.w, acc.w);
        }
    }

    float4 o = make_float4(fmaxf(acc.x, 0.f), fmaxf(acc.y, 0.f),
                           fmaxf(acc.z, 0.f), fmaxf(acc.w, 0.f));
    *reinterpret_cast<float4*>(out + (size_t)(row0 + r) * DD + col0 + tc * 4) = o;
}

extern "C" void kernel_launch(void* const* d_in, const int* in_sizes, int n_in,
                              void* d_out, int out_size, void* d_ws, size_t ws_size,
                              hipStream_t stream) {
    const float* x    = (const float*)d_in[0];   // [8,48,512]
    const float* tg   = (const float*)d_in[1];   // [8,48,512]
    const float* E    = (const float*)d_in[2];   // [512,1024]
    const float* Dy   = (const float*)d_in[3];   // [1024,512]
    const float* mixp = (const float*)d_in[4];   // scalar
    float* out = (float*)d_out;                  // [8,48,512]

    float* ws = (float*)d_ws;
    float* z_x    = ws;                               // 384*1024
    float* z_t    = z_x + (size_t)384 * 1024;
    float* xn     = z_t + (size_t)384 * 1024;
    float* tn     = xn + (size_t)384 * 1024;
    float* r_part = tn + (size_t)384 * 1024;          // 256 chunks * 48 * 1024 floats
    float* mixbuf = r_part + (size_t)256 * 48 * 1024; // 384*1024

    k_gemm_z<<<dim3(24, 16), 256, 0, stream>>>(x, tg, E, z_x, z_t);
    k_ln<<<384, 256, 0, stream>>>(z_x, z_t, xn, tn);
    k_sweep<<<1024, 256, 0, stream>>>(xn, tn, r_part);
    k_mix<<<384, 256, 0, stream>>>(r_part, mixp, mixbuf);
    k_y2<<<dim3(8, 24), 256, 0, stream>>>(mixbuf, Dy, out);
}

// Round 12
// 137.620 us; speedup vs baseline: 1.4201x; 1.0401x over previous
//
#include <hip/hip_runtime.h>
#include <math.h>

#define BB 8
#define TT 48
#define DD 512
#define NN 1024

// ---------- z = [x ; tgt_next] @ E, LDS-tiled (round-9 exact) ----------
__global__ __launch_bounds__(256) void k_gemm_z(const float* __restrict__ x,
                                                const float* __restrict__ tg,
                                                const float* __restrict__ E,
                                                float* __restrict__ z_x,
                                                float* __restrict__ z_t) {
    int rt = blockIdx.x, ct = blockIdx.y;
    int tid = threadIdx.x;
    int tr = tid >> 4;          // 0..15
    int tc = tid & 15;          // 0..15
    int row0 = rt * 32;
    int col0 = ct * 64;

    __shared__ float As[32][16];
    __shared__ float Es[16][64];

    int e2 = tid * 2;
    int sr = e2 >> 4;           // 0..31
    int sk0 = e2 & 15;
    int gr_s = row0 + sr;
    const float* srow;
    if (gr_s < BB * TT) {
        srow = x + (size_t)gr_s * DD;
    } else {
        int s = gr_s - BB * TT + 1;
        if (s > BB * TT - 1) s = BB * TT - 1;   // t=47 rows: garbage, masked by k_ln
        srow = tg + (size_t)s * DD;
    }

    int se = tid >> 4;          // 0..15
    int sc0 = (tid & 15) * 4;
    const float* erow = E + col0 + sc0;

    float4 acc0 = make_float4(0.f, 0.f, 0.f, 0.f);
    float4 acc1 = make_float4(0.f, 0.f, 0.f, 0.f);

    for (int d0 = 0; d0 < DD; d0 += 16) {
        float2 xv = *reinterpret_cast<const float2*>(srow + d0 + sk0);
        float4 ev = *reinterpret_cast<const float4*>(erow + (size_t)(d0 + se) * NN);
        __syncthreads();
        As[sr][sk0] = xv.x;
        As[sr][sk0 + 1] = xv.y;
        *reinterpret_cast<float4*>(&Es[se][sc0]) = ev;
        __syncthreads();
#pragma unroll
        for (int k = 0; k < 16; k++) {
            float a0 = As[tr][k];
            float a1 = As[tr + 16][k];
            float4 e = *reinterpret_cast<const float4*>(&Es[k][tc * 4]);
            acc0.x = fmaf(a0, e.x, acc0.x);
            acc0.y = fmaf(a0, e.y, acc0.y);
            acc0.z = fmaf(a0, e.z, acc0.z);
            acc0.w = fmaf(a0, e.w, acc0.w);
            acc1.x = fmaf(a1, e.x, acc1.x);
            acc1.y = fmaf(a1, e.y, acc1.y);
            acc1.z = fmaf(a1, e.z, acc1.z);
            acc1.w = fmaf(a1, e.w, acc1.w);
        }
    }

    int gr0 = row0 + tr, gr1 = row0 + tr + 16;
    int cbase = col0 + tc * 4;
    if (gr0 < BB * TT)
        *reinterpret_cast<float4*>(z_x + (size_t)gr0 * NN + cbase) = acc0;
    else
        *reinterpret_cast<float4*>(z_t + (size_t)(gr0 - BB * TT) * NN + cbase) = acc0;
    if (gr1 < BB * TT)
        *reinterpret_cast<float4*>(z_x + (size_t)gr1 * NN + cbase) = acc1;
    else
        *reinterpret_cast<float4*>(z_t + (size_t)(gr1 - BB * TT) * NN + cbase) = acc1;
}

// ---------- LN + relu (round-3 exact) ----------
__global__ __launch_bounds__(256) void k_ln(const float* __restrict__ z_x,
                                            const float* __restrict__ z_t,
                                            float* __restrict__ xn,
                                            float* __restrict__ tn) {
    int bt = blockIdx.x;
    int t = bt % TT;
    int tid = threadIdx.x;
    __shared__ float rs_[256], rq_[256];

    const float* src = z_x + (size_t)bt * NN;
    float v0 = src[tid], v1 = src[tid + 256], v2 = src[tid + 512], v3 = src[tid + 768];
    rs_[tid] = v0 + v1 + v2 + v3;
    rq_[tid] = v0 * v0 + v1 * v1 + v2 * v2 + v3 * v3;
    __syncthreads();
    for (int off = 128; off > 0; off >>= 1) {
        if (tid < off) { rs_[tid] += rs_[tid + off]; rq_[tid] += rq_[tid + off]; }
        __syncthreads();
    }
    float mu = rs_[0] * (1.f / NN);
    float var = rq_[0] * (1.f / NN) - mu * mu;
    float rstd = rsqrtf(var + 1e-5f);
    float* xrow = xn + (size_t)bt * NN;
    xrow[tid]       = fmaxf((v0 - mu) * rstd, 0.f);
    xrow[tid + 256] = fmaxf((v1 - mu) * rstd, 0.f);
    xrow[tid + 512] = fmaxf((v2 - mu) * rstd, 0.f);
    xrow[tid + 768] = fmaxf((v3 - mu) * rstd, 0.f);
    __syncthreads();

    float* trow = tn + (size_t)bt * NN;
    if (t < TT - 1) {
        const float* s2 = z_t + (size_t)bt * NN;
        float u0 = s2[tid], u1 = s2[tid + 256], u2 = s2[tid + 512], u3 = s2[tid + 768];
        rs_[tid] = u0 + u1 + u2 + u3;
        rq_[tid] = u0 * u0 + u1 * u1 + u2 * u2 + u3 * u3;
        __syncthreads();
        for (int off = 128; off > 0; off >>= 1) {
            if (tid < off) { rs_[tid] += rs_[tid + off]; rq_[tid] += rq_[tid + off]; }
            __syncthreads();
        }
        float mu2 = rs_[0] * (1.f / NN);
        float var2 = rq_[0] * (1.f / NN) - mu2 * mu2;
        float r2 = rsqrtf(var2 + 1e-5f);
        trow[tid]       = fmaxf((u0 - mu2) * r2, 0.f);
        trow[tid + 256] = fmaxf((u1 - mu2) * r2, 0.f);
        trow[tid + 512] = fmaxf((u2 - mu2) * r2, 0.f);
        trow[tid + 768] = fmaxf((u3 - mu2) * r2, 0.f);
    } else {
        trow[tid] = 0.f; trow[tid + 256] = 0.f; trow[tid + 512] = 0.f; trow[tid + 768] = 0.f;
    }
}

// ---------- the recurrence: G in arch VGPRs (asm-forced), weights via LDS broadcast ----------
// Block stages its whole weight slab (48 t x 64 rows = 12 KB, shared by all 4 waves:
// same (b,nc)) into LDS once. Per t: 16 uniform ds_read_b128 broadcasts (DS pipe,
// in-order, fine-grained lgkmcnt, overlaps VALU) + 192 VALU. No SMEM in the loop,
// no asm-volatile scheduling fences -> cross-iteration pipelining. mv prefetched
// one t ahead. Op order identical to rounds 5-11 -> bit-exact.

#define GI(n) float g##n = (state == 0 && nc == cc && (n) == lane) ? 0.5f : 0.f;
#define REP64(X) X(0) X(1) X(2) X(3) X(4) X(5) X(6) X(7) X(8) X(9) X(10) X(11) X(12) X(13) \
    X(14) X(15) X(16) X(17) X(18) X(19) X(20) X(21) X(22) X(23) X(24) X(25) X(26) X(27) \
    X(28) X(29) X(30) X(31) X(32) X(33) X(34) X(35) X(36) X(37) X(38) X(39) X(40) X(41) \
    X(42) X(43) X(44) X(45) X(46) X(47) X(48) X(49) X(50) X(51) X(52) X(53) X(54) X(55) \
    X(56) X(57) X(58) X(59) X(60) X(61) X(62) X(63)

#define GS(WE, n, A) { float wn_ = (WE); float tmp_;                             \
    asm("v_fmac_f32 %[a], %[w], %[g]\n\t"                                        \
        "v_mul_f32 %[t], %[w], %[m]\n\t"                                         \
        "v_max_f32 %[g], %[g], %[t]"                                             \
        : [a]"+v"(A), [g]"+v"(g##n), [t]"=&v"(tmp_)                              \
        : [w]"v"(wn_), [m]"v"(mh)); }

#define GQ(q, n0_, n1_, n2_, n3_) {                                              \
    float4 w4_ = *reinterpret_cast<const float4*>(&lw[(t << 6) + (q) * 4]);      \
    GS(w4_.x, n0_, a0) GS(w4_.y, n1_, a1) GS(w4_.z, n2_, a2) GS(w4_.w, n3_, a3) }

__global__ __launch_bounds__(256)
__attribute__((amdgpu_waves_per_eu(4, 4)))
void k_sweep(const float* __restrict__ xn,
             const float* __restrict__ tn,
             float* __restrict__ r_part) {
    int bid = blockIdx.x;
    int ccg = bid & 3, nc = (bid >> 2) & 15, b = (bid >> 6) & 7, state = bid >> 9;
    int tid = threadIdx.x;
    int lane = tid & 63;
    int wid = __builtin_amdgcn_readfirstlane(tid >> 6);
    int cc = ccg * 4 + wid;
    int n0 = nc * 64;
    int col = cc * 64 + lane;

    __shared__ float lw[TT * 64];                  // 12 KB: whole weight slab

    REP64(GI)

    const float* wb  = xn + (size_t)b * TT * NN + n0;
    const float* mvb = (state ? tn : xn) + (size_t)b * TT * NN + col;
    float* rp = r_part + ((size_t)((state * 8 + b) * 16 + nc) * TT) * NN + col;

    // stage weights: [t][64] layout, coalesced 256B rows
    for (int i = tid; i < TT * 64; i += 256)
        lw[i] = wb[(size_t)(i >> 6) * NN + (i & 63)];
    __syncthreads();

    float mv_cur = mvb[0];

#pragma unroll 1
    for (int t = 0; t < TT; t++) {
        int tn1 = (t + 1 < TT) ? t + 1 : TT - 1;
        float mv_nxt = mvb[(size_t)tn1 * NN];      // prefetch next t's mv
        float sc = (t < TT - 1) ? 0.5f : 0.0f;     // folds do_upd into the operand
        float mh = mv_cur * sc;
        float a0 = 0.f, a1 = 0.f, a2 = 0.f, a3 = 0.f;
        GQ(0,  0,  1,  2,  3)
        GQ(1,  4,  5,  6,  7)
        GQ(2,  8,  9, 10, 11)
        GQ(3, 12, 13, 14, 15)
        GQ(4, 16, 17, 18, 19)
        GQ(5, 20, 21, 22, 23)
        GQ(6, 24, 25, 26, 27)
        GQ(7, 28, 29, 30, 31)
        GQ(8, 32, 33, 34, 35)
        GQ(9, 36, 37, 38, 39)
        GQ(10, 40, 41, 42, 43)
        GQ(11, 44, 45, 46, 47)
        GQ(12, 48, 49, 50, 51)
        GQ(13, 52, 53, 54, 55)
        GQ(14, 56, 57, 58, 59)
        GQ(15, 60, 61, 62, 63)
        rp[(size_t)t * NN] = (a0 + a1) + (a2 + a3);
        mv_cur = mv_nxt;
    }
}

// ---------- reduce partials over nc + mix (round-11 exact) ----------
__global__ __launch_bounds__(256) void k_mix(const float* __restrict__ r_part,
                                             const float* __restrict__ mixp,
                                             float* __restrict__ mix) {
    int bt = blockIdx.x;            // b*TT + t
    int b = bt / TT, t = bt % TT;
    int tid = threadIdx.x;
    int c0 = tid * 4;
    float alpha = 1.f / (1.f + expf(-mixp[0]));

    float spx = 0.f, spy = 0.f, spz = 0.f, spw = 0.f;
    float stx = 0.f, sty = 0.f, stz = 0.f, stw = 0.f;
#pragma unroll
    for (int nc = 0; nc < 16; nc++) {
        int bidp = (b * 16 + nc);
        int bidt = ((8 + b) * 16 + nc);
        float4 p = *reinterpret_cast<const float4*>(r_part + ((size_t)bidp * TT + t) * NN + c0);
        float4 q = *reinterpret_cast<const float4*>(r_part + ((size_t)bidt * TT + t) * NN + c0);
        spx += p.x; spy += p.y; spz += p.z; spw += p.w;
        stx += q.x; sty += q.y; stz += q.z; stw += q.w;
    }
    float4 m4;
    m4.x = alpha * spx + (1.f - alpha) * stx;
    m4.y = alpha * spy + (1.f - alpha) * sty;
    m4.z = alpha * spz + (1.f - alpha) * stz;
    m4.w = alpha * spw + (1.f - alpha) * stw;
    *reinterpret_cast<float4*>(mix + (size_t)bt * NN + c0) = m4;
}

// ---------- y = relu(mix @ Dy) (round-11 exact) ----------
__global__ __launch_bounds__(256) void k_y2(const float* __restrict__ mix,
                                            const float* __restrict__ Dy,
                                            float* __restrict__ out) {
    int ct = blockIdx.x;            // 0..7
    int rt = blockIdx.y;            // 0..23
    int tid = threadIdx.x;
    int row0 = rt * 16;
    int col0 = ct * 64;
    int r = tid >> 4;               // 0..15
    int tc = tid & 15;              // 0..15

    __shared__ float As[16][16];
    __shared__ float Ds[16][64];

    int sr = tid >> 4, sk = tid & 15;
    int se = tid >> 4, sc0 = (tid & 15) * 4;

    float4 acc = make_float4(0.f, 0.f, 0.f, 0.f);

    for (int m0 = 0; m0 < NN; m0 += 16) {
        float av = mix[(size_t)(row0 + sr) * NN + m0 + sk];
        float4 dv = *reinterpret_cast<const float4*>(Dy + (size_t)(m0 + se) * DD + col0 + sc0);
        __syncthreads();
        As[sr][sk] = av;
        *reinterpret_cast<float4*>(&Ds[se][sc0]) = dv;
        __syncthreads();
#pragma unroll
        for (int k = 0; k < 16; k++) {
            float a = As[r][k];
            float4 e = *reinterpret_cast<const float4*>(&Ds[k][tc * 4]);
            acc.x = fmaf(a, e.x, acc.x);
            acc.y = fmaf(a, e.y, acc.y);
            acc.z = fmaf(a, e.z, acc.z);
            acc.w = fmaf(a, e.w, acc.w);
        }
    }

    float4 o = make_float4(fmaxf(acc.x, 0.f), fmaxf(acc.y, 0.f),
                           fmaxf(acc.z, 0.f), fmaxf(acc.w, 0.f));
    *reinterpret_cast<float4*>(out + (size_t)(row0 + r) * DD + col0 + tc * 4) = o;
}

extern "C" void kernel_launch(void* const* d_in, const int* in_sizes, int n_in,
                              void* d_out, int out_size, void* d_ws, size_t ws_size,
                              hipStream_t stream) {
    const float* x    = (const float*)d_in[0];   // [8,48,512]
    const float* tg   = (const float*)d_in[1];   // [8,48,512]
    const float* E    = (const float*)d_in[2];   // [512,1024]
    const float* Dy   = (const float*)d_in[3];   // [1024,512]
    const float* mixp = (const float*)d_in[4];   // scalar
    float* out = (float*)d_out;                  // [8,48,512]

    float* ws = (float*)d_ws;
    float* z_x    = ws;                               // 384*1024
    float* z_t    = z_x + (size_t)384 * 1024;
    float* xn     = z_t + (size_t)384 * 1024;
    float* tn     = xn + (size_t)384 * 1024;
    float* r_part = tn + (size_t)384 * 1024;          // 256 chunks * 48 * 1024 floats
    float* mixbuf = r_part + (size_t)256 * 48 * 1024; // 384*1024

    k_gemm_z<<<dim3(24, 16), 256, 0, stream>>>(x, tg, E, z_x, z_t);
    k_ln<<<384, 256, 0, stream>>>(z_x, z_t, xn, tn);
    k_sweep<<<1024, 256, 0, stream>>>(xn, tn, r_part);
    k_mix<<<384, 256, 0, stream>>>(r_part, mixp, mixbuf);
    k_y2<<<dim3(8, 24), 256, 0, stream>>>(mixbuf, Dy, out);
}